// Round 5
// baseline (28827.414 us; speedup 1.0000x reference)
//
#include <hip/hip_runtime.h>
#include <math.h>

typedef unsigned short u16;

#define T_STEPS 64
#define B_      256
#define EMB_    1024
#define ACT_    6
#define STOCH_  64
#define HID_    512
#define FEAT_   512
#define STATE_  576
#define G3      1536
#define TK      32
#define XPAD    68
#define WPAD    132
#define LOG2PI_ 1.8378770664093453

struct Params {
  const float *emb,*action,*reward,*eps;
  const float *bih,*bhh;
  const float *stb0,*stb1,*stb2;
  const float *epb0,*epb1,*epb2;
  const u16 *bWih,*bWhh,*bstW0,*bstW1,*bstW2,*bepW0,*bepW1,*bepW2;
  float *states;
  double *acc;   // [0]=kl [1]=emb [2]=reward
  float *out;
};

__device__ __forceinline__ float4 ld4(const float* p){ return *(const float4*)p; }
__device__ __forceinline__ float elu_f(float x){ return x > 0.f ? x : expm1f(x); }
__device__ __forceinline__ float sigmoid_f(float x){ return 1.f/(1.f+expf(-x)); }
__device__ __forceinline__ float softplus_f(float x){ return x > 20.f ? x : log1pf(expf(x)); }
__device__ __forceinline__ float bfu(u16 u){ return __uint_as_float(((unsigned)u)<<16); }

__device__ __forceinline__ double wave_sum(double v){
  #pragma unroll
  for (int o = 32; o > 0; o >>= 1) v += __shfl_down(v, o, 64);
  return v;
}

// ---------------- weight converters (fp32 -> bf16 RNE) ----------------
__global__ void convw_k(const float* __restrict__ s, u16* __restrict__ d, int n){
  const int i = blockIdx.x*256 + threadIdx.x;
  if (i < n){
    const unsigned u = __float_as_uint(s[i]);
    d[i] = (u16)((u + 0x7FFFu + ((u>>16)&1u)) >> 16);
  }
}
// Wih [1536][70] -> padded [1536][96] bf16 (zero pad)
__global__ void convwih_k(const float* __restrict__ s, u16* __restrict__ d){
  const int i = blockIdx.x*256 + threadIdx.x;   // < 1536*96
  const int n = i/96, k = i%96;
  u16 r = 0;
  if (k < 70){
    const unsigned u = __float_as_uint(s[n*70 + k]);
    r = (u16)((u + 0x7FFFu + ((u>>16)&1u)) >> 16);
  }
  d[i] = r;
}

// ---------------- scan GEMV cores ----------------
// 4-lane cluster per output row; lane l covers k = l*8 + 32*j (8 bf16 = one 16B load).

template<int K>
__device__ __forceinline__ float gemv_bf(const u16* __restrict__ W, const float* x, int n, int l){
  const u16* wr = W + (long)n*K + l*8;
  const float* xr = x + l*8;
  float a0=0.f,a1=0.f,a2=0.f,a3=0.f;
  #pragma unroll
  for (int j = 0; j < K/32; ++j){
    const float4 wq = *(const float4*)(wr + 32*j);
    const u16* wu = (const u16*)&wq;
    const float4 xa = ld4(xr + 32*j);
    const float4 xb = ld4(xr + 32*j + 4);
    a0 += bfu(wu[0])*xa.x; a1 += bfu(wu[1])*xa.y;
    a2 += bfu(wu[2])*xa.z; a3 += bfu(wu[3])*xa.w;
    a0 += bfu(wu[4])*xb.x; a1 += bfu(wu[5])*xb.y;
    a2 += bfu(wu[6])*xb.z; a3 += bfu(wu[7])*xb.w;
  }
  float a = (a0+a1)+(a2+a3);
  a += __shfl_xor(a, 1, 64);
  a += __shfl_xor(a, 2, 64);
  return a;
}

// dual GEMV, one W stream: head (k<KH) shared x; tail dual xA/xB.
template<int KH, int KT>
__device__ __forceinline__ void gemv_dual_bf(const u16* __restrict__ W, const float* xh,
                                             const float* xA, const float* xB, int n, int l,
                                             float& yA, float& yB){
  const u16* wr = W + (long)n*(KH+KT) + l*8;
  float h0=0.f,h1=0.f;
  #pragma unroll
  for (int j = 0; j < KH/32; ++j){
    const float4 wq = *(const float4*)(wr + 32*j);
    const u16* wu = (const u16*)&wq;
    const float4 xa = ld4(xh + l*8 + 32*j);
    const float4 xb = ld4(xh + l*8 + 32*j + 4);
    h0 += bfu(wu[0])*xa.x + bfu(wu[1])*xa.y + bfu(wu[2])*xa.z + bfu(wu[3])*xa.w;
    h1 += bfu(wu[4])*xb.x + bfu(wu[5])*xb.y + bfu(wu[6])*xb.z + bfu(wu[7])*xb.w;
  }
  const u16* wt = wr + KH;
  float a0=0.f,a1=0.f,b0=0.f,b1=0.f;
  #pragma unroll
  for (int j = 0; j < KT/32; ++j){
    const float4 wq = *(const float4*)(wt + 32*j);
    const u16* wu = (const u16*)&wq;
    const float4 va = ld4(xA + l*8 + 32*j);
    const float4 vb = ld4(xA + l*8 + 32*j + 4);
    const float4 wa_ = ld4(xB + l*8 + 32*j);
    const float4 wb_ = ld4(xB + l*8 + 32*j + 4);
    const float w0=bfu(wu[0]), w1=bfu(wu[1]), w2=bfu(wu[2]), w3=bfu(wu[3]);
    const float w4=bfu(wu[4]), w5=bfu(wu[5]), w6=bfu(wu[6]), w7=bfu(wu[7]);
    a0 += w0*va.x + w1*va.y + w2*va.z + w3*va.w;
    a1 += w4*vb.x + w5*vb.y + w6*vb.z + w7*vb.w;
    b0 += w0*wa_.x + w1*wa_.y + w2*wa_.z + w3*wa_.w;
    b1 += w4*wb_.x + w5*wb_.y + w6*wb_.z + w7*wb_.w;
  }
  float ra = (h0+h1)+(a0+a1);
  float rb = (h0+h1)+(b0+b1);
  ra += __shfl_xor(ra, 1, 64); ra += __shfl_xor(ra, 2, 64);
  rb += __shfl_xor(rb, 1, 64); rb += __shfl_xor(rb, 2, 64);
  yA = ra; yB = rb;
}

// ---------------- scan kernel: one block per batch row ----------------
__global__ void __launch_bounds__(1024) scan_kernel(Params p)
{
  const int tid = threadIdx.x;
  const int r = blockIdx.x;
  const int c = tid >> 2, l = tid & 3;   // 256 clusters of 4 lanes

  __shared__ __align__(16) float hs[STATE_];
  __shared__ __align__(16) float sa[96];        // [s(64) | a(6) | 0-pad]
  __shared__ __align__(16) float ep_[EMB_];
  __shared__ __align__(16) float pe0[512], pe1[512];
  __shared__ __align__(16) float pemb[EMB_];
  __shared__ __align__(16) float gi[G3], gh[G3];
  __shared__ __align__(16) float po0[512], po1[512], pr0[512], pr1[512];
  __shared__ __align__(16) float po2[128], pr2[128];

  double klacc = 0.0;
  if (tid < STATE_) hs[tid] = 0.f;
  __syncthreads();

  for (int t = 0; t < T_STEPS; ++t){
    // ---- emb_prev row + sa = [s_{t-1} | a_t | 0] ----
    {
      const long eb = ((long)(t > 0 ? t-1 : 0)*B_ + r)*EMB_;
      ep_[tid] = p.emb[eb + tid];
      if (tid >= 1024-96){
        const int i = tid - (1024-96);
        float v = 0.f;
        if (i < 64)      v = hs[512 + i];
        else if (i < 70) v = p.action[((long)t*B_ + r)*ACT_ + (i - 64)];
        sa[i] = v;
      }
    }
    __syncthreads();
    // ---- pe0 = elu([h|s]_{t-1} @ epW0^T + b) ----
    #pragma unroll
    for (int ps = 0; ps < 2; ++ps){
      const int n = ps*256 + c;
      const float v = gemv_bf<STATE_>(p.bepW0, hs, n, l);
      if (l == 0) pe0[n] = elu_f(v + p.epb0[n]);
    }
    __syncthreads();
    // ---- pe1 ----
    #pragma unroll
    for (int ps = 0; ps < 2; ++ps){
      const int n = ps*256 + c;
      const float v = gemv_bf<512>(p.bepW1, pe0, n, l);
      if (l == 0) pe1[n] = elu_f(v + p.epb1[n]);
    }
    __syncthreads();
    // ---- pemb ; gh ; gi (all read pre-update hs/sa) ----
    #pragma unroll
    for (int ps = 0; ps < 4; ++ps){
      const int n = ps*256 + c;
      const float v = gemv_bf<512>(p.bepW2, pe1, n, l);
      if (l == 0) pemb[n] = v + p.epb2[n];
    }
    #pragma unroll
    for (int ps = 0; ps < 6; ++ps){
      const int n = ps*256 + c;
      const float v = gemv_bf<512>(p.bWhh, hs, n, l);
      if (l == 0) gh[n] = v + p.bhh[n];
    }
    #pragma unroll
    for (int ps = 0; ps < 6; ++ps){
      const int n = ps*256 + c;
      const float v = gemv_bf<96>(p.bWih, sa, n, l);
      if (l == 0) gi[n] = v + p.bih[n];
    }
    __syncthreads();
    // ---- GRU combine -> h_t ----
    if (tid < 512){
      const int j = tid;
      const float ir = gi[j], iz = gi[512+j], in_ = gi[1024+j];
      const float hr = gh[j], hz = gh[512+j], hn  = gh[1024+j];
      const float rr = sigmoid_f(ir + hr);
      const float z  = sigmoid_f(iz + hz);
      const float nn = tanhf(in_ + rr*hn);
      const float hv = (1.f - z)*nn + z*hs[j];
      hs[j] = hv;
      p.states[((long)t*B_ + r)*STATE_ + j] = hv;
    }
    __syncthreads();
    // ---- st0 dual: head h_t shared; tails emb_prev (post) / pemb (prior) ----
    #pragma unroll
    for (int ps = 0; ps < 2; ++ps){
      const int n = ps*256 + c;
      float vA, vB;
      gemv_dual_bf<512, 1024>(p.bstW0, hs, ep_, pemb, n, l, vA, vB);
      if (l == 0){
        po0[n] = elu_f(vA + p.stb0[n]);
        pr0[n] = elu_f(vB + p.stb0[n]);
      }
    }
    __syncthreads();
    // ---- st1 dual ----
    #pragma unroll
    for (int ps = 0; ps < 2; ++ps){
      const int n = ps*256 + c;
      float vA, vB;
      gemv_dual_bf<0, 512>(p.bstW1, po0, po0, pr0, n, l, vA, vB);
      if (l == 0){
        po1[n] = elu_f(vA + p.stb1[n]);
        pr1[n] = elu_f(vB + p.stb1[n]);
      }
    }
    __syncthreads();
    // ---- st2 dual: N=128 ----
    if (c < 128){
      float vA, vB;
      gemv_dual_bf<0, 512>(p.bstW2, po1, po1, pr1, c, l, vA, vB);
      if (l == 0){
        po2[c] = vA + p.stb2[c];
        pr2[c] = vB + p.stb2[c];
      }
    }
    __syncthreads();
    // ---- KL(t) + sample s_t ----
    if (tid < 64){
      const int j = tid;
      const float qmu = po2[j],  qsr = po2[64+j];
      const float pmu = pr2[j],  psr = pr2[64+j];
      const float qstd = softplus_f(qsr) + 1e-4f;
      const float pstd = softplus_f(psr) + 1e-4f;
      const float dm = qmu - pmu;
      klacc += (double)(logf(pstd/qstd) + (qstd*qstd + dm*dm)/(2.f*pstd*pstd) - 0.5f);
      const float sv = qmu + qstd * p.eps[((long)t*B_ + r)*STOCH_ + j];
      hs[512 + j] = sv;
      p.states[((long)t*B_ + r)*STATE_ + 512 + j] = sv;
    }
    __syncthreads();
  }

  if (tid < 64){
    const double s = wave_sum(klacc);
    if (tid == 0) atomicAdd(&p.acc[0], s);
  }
}

// ---------------- tail head kernels (R4-proven) ----------------

struct SmemT { float X[2][TK][XPAD]; float W[2][TK][WPAD]; };

template<class XLD, class WLD>
__device__ __forceinline__ void gemm_tile(SmemT* sm, XLD xld, WLD wld, int nkt, float acc[4][4])
{
  const int tid = threadIdx.x;
  const int r0 = (tid >> 5) * 4;
  const int c0 = (tid & 31) * 4;
  const int sr = tid & 255;
  const int lr = sr >> 2, q = sr & 3;
  const bool lo = tid < 256;
  float4 xa, xb, wa, wb;
  if (lo) { xa = xld(lr, q*4);      xb = xld(lr, 16 + q*4);
            wa = wld(64+lr, q*4);   wb = wld(64+lr, 16 + q*4); }
  else    { wa = wld(lr, q*4);      wb = wld(lr, 16 + q*4); }
  int cur = 0;
  #pragma unroll
  for (int c = 0; c < 4; ++c) {
    if (lo) {
      sm->X[0][q*4+c][lr]      = ((const float*)&xa)[c];
      sm->X[0][16+q*4+c][lr]   = ((const float*)&xb)[c];
      sm->W[0][q*4+c][64+lr]   = ((const float*)&wa)[c];
      sm->W[0][16+q*4+c][64+lr]= ((const float*)&wb)[c];
    } else {
      sm->W[0][q*4+c][lr]      = ((const float*)&wa)[c];
      sm->W[0][16+q*4+c][lr]   = ((const float*)&wb)[c];
    }
  }
  for (int kt = 1; kt < nkt; ++kt) {
    __syncthreads();
    const int kb = kt*TK;
    if (lo) { xa = xld(lr, kb + q*4);    xb = xld(lr, kb + 16 + q*4);
              wa = wld(64+lr, kb + q*4); wb = wld(64+lr, kb + 16 + q*4); }
    else    { wa = wld(lr, kb + q*4);    wb = wld(lr, kb + 16 + q*4); }
    #pragma unroll
    for (int kk = 0; kk < TK; ++kk) {
      const float4 xv = *(const float4*)&sm->X[cur][kk][r0];
      const float4 wv = *(const float4*)&sm->W[cur][kk][c0];
      const float xs_[4] = {xv.x,xv.y,xv.z,xv.w};
      const float ws_[4] = {wv.x,wv.y,wv.z,wv.w};
      #pragma unroll
      for (int i = 0; i < 4; ++i)
        #pragma unroll
        for (int j = 0; j < 4; ++j) acc[i][j] += xs_[i]*ws_[j];
    }
    const int nxt = cur ^ 1;
    #pragma unroll
    for (int c = 0; c < 4; ++c) {
      if (lo) {
        sm->X[nxt][q*4+c][lr]      = ((const float*)&xa)[c];
        sm->X[nxt][16+q*4+c][lr]   = ((const float*)&xb)[c];
        sm->W[nxt][q*4+c][64+lr]   = ((const float*)&wa)[c];
        sm->W[nxt][16+q*4+c][64+lr]= ((const float*)&wb)[c];
      } else {
        sm->W[nxt][q*4+c][lr]      = ((const float*)&wa)[c];
        sm->W[nxt][16+q*4+c][lr]   = ((const float*)&wb)[c];
      }
    }
    cur = nxt;
  }
  __syncthreads();
  #pragma unroll
  for (int kk = 0; kk < TK; ++kk) {
    const float4 xv = *(const float4*)&sm->X[cur][kk][r0];
    const float4 wv = *(const float4*)&sm->W[cur][kk][c0];
    const float xs_[4] = {xv.x,xv.y,xv.z,xv.w};
    const float ws_[4] = {wv.x,wv.y,wv.z,wv.w};
    #pragma unroll
    for (int i = 0; i < 4; ++i)
      #pragma unroll
      for (int j = 0; j < 4; ++j) acc[i][j] += xs_[i]*ws_[j];
  }
}

__device__ __forceinline__ void store_tile(const float acc[4][4], const float* bias,
                                           float* C, int ldc, int row0, int col0, bool act)
{
  const int tid = threadIdx.x;
  const int r0 = (tid>>5)*4, c0 = (tid&31)*4;
  const float4 bi = ld4(bias + col0 + c0);
  #pragma unroll
  for (int i = 0; i < 4; ++i) {
    float4 v;
    v.x = acc[i][0] + bi.x; v.y = acc[i][1] + bi.y;
    v.z = acc[i][2] + bi.z; v.w = acc[i][3] + bi.w;
    if (act) { v.x=elu_f(v.x); v.y=elu_f(v.y); v.z=elu_f(v.z); v.w=elu_f(v.w); }
    *(float4*)&C[(long)(row0+r0+i)*ldc + col0 + c0] = v;
  }
}

__global__ void __launch_bounds__(512) mlp_gemm(const float* __restrict__ X, int ldx,
                                                const float* __restrict__ W, int K,
                                                const float* __restrict__ bias,
                                                float* __restrict__ Y, int ldy,
                                                int NT, int act)
{
  __shared__ SmemT sm;
  const int u = blockIdx.x;
  const int mt = u / NT, nt = u % NT;
  float acc[4][4] = {};
  auto xld = [&](int r,int k){ return ld4(X + (long)(mt*64+r)*ldx + k); };
  auto wld = [&](int n,int k){ return ld4(W + (long)(nt*128+n)*K + k); };
  gemm_tile(&sm, xld, wld, K/TK, acc);
  store_tile(acc, bias, Y, ldy, mt*64, nt*128, act != 0);
}

__global__ void __launch_bounds__(512) emb_loss_k(const float* __restrict__ X,
                                                  const float* __restrict__ W,
                                                  const float* __restrict__ bias,
                                                  const float* __restrict__ tgt,
                                                  double* accp)
{
  __shared__ SmemT sm;
  const int u = blockIdx.x;
  const int mt = u / 8, nt = u % 8;
  float acc[4][4] = {};
  auto xld = [&](int r,int k){ return ld4(X + (long)(mt*64+r)*FEAT_ + k); };
  auto wld = [&](int n,int k){ return ld4(W + (long)(nt*128+n)*FEAT_ + k); };
  gemm_tile(&sm, xld, wld, FEAT_/TK, acc);
  const int tid = threadIdx.x;
  const int r0 = (tid>>5)*4, c0 = (tid&31)*4;
  const float4 bi = ld4(bias + nt*128 + c0);
  double ls = 0.0;
  #pragma unroll
  for (int i = 0; i < 4; ++i) {
    const float4 tv = ld4(tgt + (long)(mt*64+r0+i)*EMB_ + nt*128 + c0);
    const float d0 = tv.x - (acc[i][0]+bi.x);
    const float d1 = tv.y - (acc[i][1]+bi.y);
    const float d2 = tv.z - (acc[i][2]+bi.z);
    const float d3 = tv.w - (acc[i][3]+bi.w);
    ls += 0.5*((double)d0*d0 + (double)d1*d1 + (double)d2*d2 + (double)d3*d3);
  }
  ls = wave_sum(ls);
  if ((tid & 63) == 0) atomicAdd(accp, ls);
}

__global__ void __launch_bounds__(512) rp_loss_k(const float* __restrict__ h2,
                                                 const float* __restrict__ W2,
                                                 const float* __restrict__ b2,
                                                 const float* __restrict__ reward,
                                                 double* accp)
{
  const int tid = threadIdx.x;
  const int lane = tid & 63;
  const int wid = blockIdx.x*8 + (tid >> 6);
  double ls = 0.0;
  for (int row = wid; row < 4096; row += 512) {
    float part = 0.f;
    for (int k = lane*4; k < FEAT_; k += 64*4) {
      const float4 hv = ld4(h2 + (long)row*FEAT_ + k);
      const float4 wv = ld4(W2 + k);
      part += hv.x*wv.x + hv.y*wv.y + hv.z*wv.z + hv.w*wv.w;
    }
    #pragma unroll
    for (int o = 32; o > 0; o >>= 1) part += __shfl_down(part, o, 64);
    if (lane == 0) {
      const float mu = part + b2[0];
      const float d = reward[row] - mu;
      ls += 0.5 * (double)d * (double)d;
    }
  }
  if (lane == 0) atomicAdd(accp, ls);
}

__global__ void final_k(const double* acc, float* out)
{
  const double tot = (acc[0] + acc[1] + acc[2]) / (double)(T_STEPS * B_)
                   + 512.0 * LOG2PI_ + 0.5 * LOG2PI_;
  out[0] = (float)tot;
}

extern "C" void kernel_launch(void* const* d_in, const int* in_sizes, int n_in,
                              void* d_out, int out_size, void* d_ws, size_t ws_size,
                              hipStream_t stream) {
  const float* emb    = (const float*)d_in[0];
  const float* action = (const float*)d_in[1];
  const float* reward = (const float*)d_in[2];
  const float* eps    = (const float*)d_in[3];
  const float* Wih  = (const float*)d_in[4];  const float* bih  = (const float*)d_in[5];
  const float* Whh  = (const float*)d_in[6];  const float* bhh  = (const float*)d_in[7];
  const float* stW0 = (const float*)d_in[8];  const float* stb0 = (const float*)d_in[9];
  const float* stW1 = (const float*)d_in[10]; const float* stb1 = (const float*)d_in[11];
  const float* stW2 = (const float*)d_in[12]; const float* stb2 = (const float*)d_in[13];
  const float* epW0 = (const float*)d_in[14]; const float* epb0 = (const float*)d_in[15];
  const float* epW1 = (const float*)d_in[16]; const float* epb1 = (const float*)d_in[17];
  const float* epW2 = (const float*)d_in[18]; const float* epb2 = (const float*)d_in[19];
  const float* rpW0 = (const float*)d_in[20]; const float* rpb0 = (const float*)d_in[21];
  const float* rpW1 = (const float*)d_in[22]; const float* rpb1 = (const float*)d_in[23];
  const float* rpW2 = (const float*)d_in[24]; const float* rpb2 = (const float*)d_in[25];

  double* acc = (double*)d_ws;
  float* f = (float*)((char*)d_ws + 256);
  float* states = f;  f += (long)16384 * STATE_;
  float* h1 = f;      f += (long)4096 * FEAT_;
  float* h2 = f;      f += (long)4096 * FEAT_;
  u16* bw = (u16*)f;
  u16* bepW0 = bw;    bw += 294912;
  u16* bepW1 = bw;    bw += 262144;
  u16* bepW2 = bw;    bw += 524288;
  u16* bWhh  = bw;    bw += 786432;
  u16* bstW0 = bw;    bw += 786432;
  u16* bstW1 = bw;    bw += 262144;
  u16* bstW2 = bw;    bw += 65536;
  u16* bWih  = bw;    bw += 147456;
  // total ws ~61 MB

  hipMemsetAsync(d_ws, 0, 256, stream);

  convw_k<<<(294912+255)/256, 256, 0, stream>>>(epW0, bepW0, 294912);
  convw_k<<<(262144+255)/256, 256, 0, stream>>>(epW1, bepW1, 262144);
  convw_k<<<(524288+255)/256, 256, 0, stream>>>(epW2, bepW2, 524288);
  convw_k<<<(786432+255)/256, 256, 0, stream>>>(Whh,  bWhh,  786432);
  convw_k<<<(786432+255)/256, 256, 0, stream>>>(stW0, bstW0, 786432);
  convw_k<<<(262144+255)/256, 256, 0, stream>>>(stW1, bstW1, 262144);
  convw_k<<<(65536+255)/256,  256, 0, stream>>>(stW2, bstW2, 65536);
  convwih_k<<<(147456+255)/256, 256, 0, stream>>>(Wih, bWih);

  Params p;
  p.emb = emb; p.action = action; p.reward = reward; p.eps = eps;
  p.bih = bih; p.bhh = bhh;
  p.stb0 = stb0; p.stb1 = stb1; p.stb2 = stb2;
  p.epb0 = epb0; p.epb1 = epb1; p.epb2 = epb2;
  p.bWih = bWih; p.bWhh = bWhh;
  p.bstW0 = bstW0; p.bstW1 = bstW1; p.bstW2 = bstW2;
  p.bepW0 = bepW0; p.bepW1 = bepW1; p.bepW2 = bepW2;
  p.states = states;
  p.acc = acc;
  p.out = (float*)d_out;

  scan_kernel<<<B_, 1024, 0, stream>>>(p);

  for (int ch = 0; ch < 4; ++ch) {
    const float* xs = states + (long)ch*4096*STATE_;
    mlp_gemm<<<64*4, 512, 0, stream>>>(xs, STATE_, epW0, STATE_, epb0, h1, FEAT_, 4, 1);
    mlp_gemm<<<64*4, 512, 0, stream>>>(h1, FEAT_, epW1, FEAT_, epb1, h2, FEAT_, 4, 1);
    emb_loss_k<<<64*8, 512, 0, stream>>>(h2, epW2, epb2, emb + (long)ch*4096*EMB_, acc + 1);
  }
  for (int ch = 0; ch < 4; ++ch) {
    const float* xs = states + (long)ch*4096*STATE_;
    mlp_gemm<<<64*4, 512, 0, stream>>>(xs, STATE_, rpW0, STATE_, rpb0, h1, FEAT_, 4, 1);
    mlp_gemm<<<64*4, 512, 0, stream>>>(h1, FEAT_, rpW1, FEAT_, rpb1, h2, FEAT_, 4, 1);
    rp_loss_k<<<64, 512, 0, stream>>>(h2, rpW2, rpb2, reward + (long)ch*4096, acc + 2);
  }
  final_k<<<1, 1, 0, stream>>>(acc, p.out);
}

// Round 6
// 13576.479 us; speedup vs baseline: 2.1233x; 2.1233x over previous
//
#include <hip/hip_runtime.h>
#include <math.h>

#define T_STEPS 64
#define B_      256
#define EMB_    1024
#define ACT_    6
#define STOCH_  64
#define HID_    512
#define FEAT_   512
#define STATE_  576
#define G3      1536
#define TK      32
#define XPAD    68
#define WPAD    132
#define LOG2PI_ 1.8378770664093453

struct Params {
  const float *emb,*action,*reward,*eps;
  const float *Wih,*bih,*Whh,*bhh;
  const float *stW0,*stb0,*stW1,*stb1,*stW2,*stb2;
  const float *epW0,*epb0,*epW1,*epb1,*epW2,*epb2;
  float *states;
  double *acc;   // [0]=kl [1]=emb [2]=reward
  float *out;
};

__device__ __forceinline__ float4 ld4(const float* p){ return *(const float4*)p; }
__device__ __forceinline__ float elu_f(float x){ return x > 0.f ? x : expm1f(x); }
__device__ __forceinline__ float sigmoid_f(float x){ return 1.f/(1.f+expf(-x)); }
__device__ __forceinline__ float softplus_f(float x){ return x > 20.f ? x : log1pf(expf(x)); }
__device__ __forceinline__ float dot4(float4 a, float4 b){
  return a.x*b.x + a.y*b.y + a.z*b.z + a.w*b.w;
}
__device__ __forceinline__ float qred(float a){   // reduce over 4-lane cluster
  a += __shfl_xor(a, 1, 64);
  a += __shfl_xor(a, 2, 64);
  return a;
}

__device__ __forceinline__ double wave_sum(double v){
  #pragma unroll
  for (int o = 32; o > 0; o >>= 1) v += __shfl_down(v, o, 64);
  return v;
}

// ---------------- scan GEMV cores (fp32, convoy-friendly) ----------------
// 4-lane cluster handles TWO output rows n0,n1 sharing one x stream:
// 2 W loads in flight per x load -> 2x MLP vs R4.

template<int K>
__device__ __forceinline__ void gemv2(const float* __restrict__ W, const float* x,
                                      int n0, int n1, int l, float& y0, float& y1){
  const float* w0 = W + (long)n0*K + l*4;
  const float* w1 = W + (long)n1*K + l*4;
  const float* xr = x + l*4;
  float a0=0.f, a1=0.f;
  #pragma unroll 8
  for (int j = 0; j < K/16; ++j){
    const float4 xv = ld4(xr + 16*j);
    const float4 wa = ld4(w0 + 16*j);
    const float4 wb = ld4(w1 + 16*j);
    a0 += dot4(wa, xv);
    a1 += dot4(wb, xv);
  }
  y0 = qred(a0); y1 = qred(a1);
}

// st0: K=1536 = 512 head (shared x = h_t) + 1024 tail (xA=emb_prev for posterior,
// xB=pre_emb for prior); 2 rows x 2 streams = 4 dots, one W stream pair.
__device__ __forceinline__ void st0_quad(const float* __restrict__ W, const float* xh,
                                         const float* xA, const float* xB,
                                         int n0, int n1, int l,
                                         float& pA0, float& pA1, float& pB0, float& pB1){
  const float* w0 = W + (long)n0*G3 + l*4;
  const float* w1 = W + (long)n1*G3 + l*4;
  float h0=0.f, h1=0.f;
  #pragma unroll 8
  for (int j = 0; j < 512/16; ++j){
    const float4 xv = ld4(xh + l*4 + 16*j);
    const float4 wa = ld4(w0 + 16*j);
    const float4 wb = ld4(w1 + 16*j);
    h0 += dot4(wa, xv);
    h1 += dot4(wb, xv);
  }
  const float* t0 = w0 + 512;
  const float* t1 = w1 + 512;
  float a0=0.f, a1=0.f, b0=0.f, b1=0.f;
  #pragma unroll 4
  for (int j = 0; j < 1024/16; ++j){
    const float4 va = ld4(xA + l*4 + 16*j);
    const float4 vb = ld4(xB + l*4 + 16*j);
    const float4 wa = ld4(t0 + 16*j);
    const float4 wb = ld4(t1 + 16*j);
    a0 += dot4(wa, va); b0 += dot4(wa, vb);
    a1 += dot4(wb, va); b1 += dot4(wb, vb);
  }
  pA0 = qred(h0 + a0); pB0 = qred(h0 + b0);
  pA1 = qred(h1 + a1); pB1 = qred(h1 + b1);
}

// st1/st2: K=512, 2 rows x 2 x-streams (posterior/prior), one W stream pair.
template<int K>
__device__ __forceinline__ void quad2(const float* __restrict__ W,
                                      const float* xA, const float* xB,
                                      int n0, int n1, int l,
                                      float& pA0, float& pA1, float& pB0, float& pB1){
  const float* w0 = W + (long)n0*K + l*4;
  const float* w1 = W + (long)n1*K + l*4;
  float a0=0.f, a1=0.f, b0=0.f, b1=0.f;
  #pragma unroll 4
  for (int j = 0; j < K/16; ++j){
    const float4 va = ld4(xA + l*4 + 16*j);
    const float4 vb = ld4(xB + l*4 + 16*j);
    const float4 wa = ld4(w0 + 16*j);
    const float4 wb = ld4(w1 + 16*j);
    a0 += dot4(wa, va); b0 += dot4(wa, vb);
    a1 += dot4(wb, va); b1 += dot4(wb, vb);
  }
  pA0 = qred(a0); pB0 = qred(b0);
  pA1 = qred(a1); pB1 = qred(b1);
}

// K=70 rows (Wih), unaligned: scalar loads, dual-row.
__device__ __forceinline__ void gemv70_2(const float* __restrict__ W, const float* x,
                                         int n0, int n1, int l, float& y0, float& y1){
  const float* w0 = W + (long)n0*70;
  const float* w1 = W + (long)n1*70;
  float a0=0.f, a1=0.f;
  #pragma unroll
  for (int j = 0; j < 4; ++j){
    const int k = l*4 + 16*j;
    #pragma unroll
    for (int c2 = 0; c2 < 4; ++c2){
      a0 += w0[k+c2]*x[k+c2];
      a1 += w1[k+c2]*x[k+c2];
    }
  }
  if (l == 0){
    #pragma unroll
    for (int k = 64; k < 70; ++k){ a0 += w0[k]*x[k]; a1 += w1[k]*x[k]; }
  }
  y0 = qred(a0); y1 = qred(a1);
}

// ---------------- scan kernel: one block per batch row, 512 threads ----------------
__global__ void __launch_bounds__(512) scan_kernel(Params p)
{
  const int tid = threadIdx.x;
  const int r = blockIdx.x;
  const int c = tid >> 2, l = tid & 3;   // 128 clusters of 4 lanes

  __shared__ __align__(16) float hs[STATE_];   // [h(512) | s(64)]
  __shared__ __align__(16) float sa[80];       // [s(64) | a(6) | pad]
  __shared__ __align__(16) float ep_[EMB_];
  __shared__ __align__(16) float pe0[512], pe1[512];
  __shared__ __align__(16) float pemb[EMB_];
  __shared__ __align__(16) float gi[G3], gh[G3];
  __shared__ __align__(16) float po0[512], po1[512], pr0[512], pr1[512];
  __shared__ __align__(16) float po2[128], pr2[128];

  double klacc = 0.0;
  if (tid < STATE_) hs[tid] = 0.f;
  __syncthreads();

  for (int t = 0; t < T_STEPS; ++t){
    // ---- prologue: emb_prev row + sa = [s_{t-1} | a_t | 0] ----
    {
      const long eb = ((long)(t > 0 ? t-1 : 0)*B_ + r)*EMB_;
      ep_[tid]       = p.emb[eb + tid];
      ep_[tid + 512] = p.emb[eb + 512 + tid];
      if (tid < 80){
        float v = 0.f;
        if (tid < 64)      v = hs[512 + tid];
        else if (tid < 70) v = p.action[((long)t*B_ + r)*ACT_ + (tid - 64)];
        sa[tid] = v;
      }
    }
    __syncthreads();
    // ---- S_A: pe0 (2p), gh (6p), gi (6p) — all read h/s_{t-1} ----
    #pragma unroll
    for (int ps = 0; ps < 2; ++ps){
      const int n0 = ps*256 + c, n1 = n0 + 128;
      float y0, y1;
      gemv2<STATE_>(p.epW0, hs, n0, n1, l, y0, y1);
      if (l == 0){
        pe0[n0] = elu_f(y0 + p.epb0[n0]);
        pe0[n1] = elu_f(y1 + p.epb0[n1]);
      }
    }
    #pragma unroll
    for (int ps = 0; ps < 6; ++ps){
      const int n0 = ps*256 + c, n1 = n0 + 128;
      float y0, y1;
      gemv2<HID_>(p.Whh, hs, n0, n1, l, y0, y1);
      if (l == 0){
        gh[n0] = y0 + p.bhh[n0];
        gh[n1] = y1 + p.bhh[n1];
      }
    }
    #pragma unroll
    for (int ps = 0; ps < 6; ++ps){
      const int n0 = ps*256 + c, n1 = n0 + 128;
      float y0, y1;
      gemv70_2(p.Wih, sa, n0, n1, l, y0, y1);
      if (l == 0){
        gi[n0] = y0 + p.bih[n0];
        gi[n1] = y1 + p.bih[n1];
      }
    }
    __syncthreads();
    // ---- S_B: pe1 (2p) ----
    #pragma unroll
    for (int ps = 0; ps < 2; ++ps){
      const int n0 = ps*256 + c, n1 = n0 + 128;
      float y0, y1;
      gemv2<FEAT_>(p.epW1, pe0, n0, n1, l, y0, y1);
      if (l == 0){
        pe1[n0] = elu_f(y0 + p.epb1[n0]);
        pe1[n1] = elu_f(y1 + p.epb1[n1]);
      }
    }
    __syncthreads();
    // ---- S_C: pemb (4p) + GRU combine -> h_t (disjoint LDS) ----
    #pragma unroll
    for (int ps = 0; ps < 4; ++ps){
      const int n0 = ps*256 + c, n1 = n0 + 128;
      float y0, y1;
      gemv2<FEAT_>(p.epW2, pe1, n0, n1, l, y0, y1);
      if (l == 0){
        pemb[n0] = y0 + p.epb2[n0];
        pemb[n1] = y1 + p.epb2[n1];
      }
    }
    {
      const int j = tid;
      const float ir = gi[j], iz = gi[512+j], in_ = gi[1024+j];
      const float hr = gh[j], hz = gh[512+j], hn  = gh[1024+j];
      const float rr = sigmoid_f(ir + hr);
      const float z  = sigmoid_f(iz + hz);
      const float nn = tanhf(in_ + rr*hn);
      const float hv = (1.f - z)*nn + z*hs[j];
      hs[j] = hv;
      p.states[((long)t*B_ + r)*STATE_ + j] = hv;
    }
    __syncthreads();
    // ---- S_D: st0 quad (2p) ----
    #pragma unroll
    for (int ps = 0; ps < 2; ++ps){
      const int n0 = ps*256 + c, n1 = n0 + 128;
      float pA0, pA1, pB0, pB1;
      st0_quad(p.stW0, hs, ep_, pemb, n0, n1, l, pA0, pA1, pB0, pB1);
      if (l == 0){
        po0[n0] = elu_f(pA0 + p.stb0[n0]);
        po0[n1] = elu_f(pA1 + p.stb0[n1]);
        pr0[n0] = elu_f(pB0 + p.stb0[n0]);
        pr0[n1] = elu_f(pB1 + p.stb0[n1]);
      }
    }
    __syncthreads();
    // ---- S_E: st1 quad (2p) ----
    #pragma unroll
    for (int ps = 0; ps < 2; ++ps){
      const int n0 = ps*256 + c, n1 = n0 + 128;
      float pA0, pA1, pB0, pB1;
      quad2<FEAT_>(p.stW1, po0, pr0, n0, n1, l, pA0, pA1, pB0, pB1);
      if (l == 0){
        po1[n0] = elu_f(pA0 + p.stb1[n0]);
        po1[n1] = elu_f(pA1 + p.stb1[n1]);
        pr1[n0] = elu_f(pB0 + p.stb1[n0]);
        pr1[n1] = elu_f(pB1 + p.stb1[n1]);
      }
    }
    __syncthreads();
    // ---- S_F: st2 quad (1p, clusters 0..63) ----
    if (c < 64){
      const int n0 = c, n1 = c + 64;
      float pA0, pA1, pB0, pB1;
      quad2<FEAT_>(p.stW2, po1, pr1, n0, n1, l, pA0, pA1, pB0, pB1);
      if (l == 0){
        po2[n0] = pA0 + p.stb2[n0];
        po2[n1] = pA1 + p.stb2[n1];
        pr2[n0] = pB0 + p.stb2[n0];
        pr2[n1] = pB1 + p.stb2[n1];
      }
    }
    __syncthreads();
    // ---- S_G: KL(t) + sample s_t ----
    if (tid < 64){
      const int j = tid;
      const float qmu = po2[j],  qsr = po2[64+j];
      const float pmu = pr2[j],  psr = pr2[64+j];
      const float qstd = softplus_f(qsr) + 1e-4f;
      const float pstd = softplus_f(psr) + 1e-4f;
      const float dm = qmu - pmu;
      klacc += (double)(logf(pstd/qstd) + (qstd*qstd + dm*dm)/(2.f*pstd*pstd) - 0.5f);
      const float sv = qmu + qstd * p.eps[((long)t*B_ + r)*STOCH_ + j];
      hs[512 + j] = sv;
      p.states[((long)t*B_ + r)*STATE_ + 512 + j] = sv;
    }
    __syncthreads();
  }

  if (tid < 64){
    const double s = wave_sum(klacc);
    if (tid == 0) atomicAdd(&p.acc[0], s);
  }
}

// ---------------- tail head kernels (R4-proven, unchanged) ----------------

struct SmemT { float X[2][TK][XPAD]; float W[2][TK][WPAD]; };

template<class XLD, class WLD>
__device__ __forceinline__ void gemm_tile(SmemT* sm, XLD xld, WLD wld, int nkt, float acc[4][4])
{
  const int tid = threadIdx.x;
  const int r0 = (tid >> 5) * 4;
  const int c0 = (tid & 31) * 4;
  const int sr = tid & 255;
  const int lr = sr >> 2, q = sr & 3;
  const bool lo = tid < 256;
  float4 xa, xb, wa, wb;
  if (lo) { xa = xld(lr, q*4);      xb = xld(lr, 16 + q*4);
            wa = wld(64+lr, q*4);   wb = wld(64+lr, 16 + q*4); }
  else    { wa = wld(lr, q*4);      wb = wld(lr, 16 + q*4); }
  int cur = 0;
  #pragma unroll
  for (int c = 0; c < 4; ++c) {
    if (lo) {
      sm->X[0][q*4+c][lr]      = ((const float*)&xa)[c];
      sm->X[0][16+q*4+c][lr]   = ((const float*)&xb)[c];
      sm->W[0][q*4+c][64+lr]   = ((const float*)&wa)[c];
      sm->W[0][16+q*4+c][64+lr]= ((const float*)&wb)[c];
    } else {
      sm->W[0][q*4+c][lr]      = ((const float*)&wa)[c];
      sm->W[0][16+q*4+c][lr]   = ((const float*)&wb)[c];
    }
  }
  for (int kt = 1; kt < nkt; ++kt) {
    __syncthreads();
    const int kb = kt*TK;
    if (lo) { xa = xld(lr, kb + q*4);    xb = xld(lr, kb + 16 + q*4);
              wa = wld(64+lr, kb + q*4); wb = wld(64+lr, kb + 16 + q*4); }
    else    { wa = wld(lr, kb + q*4);    wb = wld(lr, kb + 16 + q*4); }
    #pragma unroll
    for (int kk = 0; kk < TK; ++kk) {
      const float4 xv = *(const float4*)&sm->X[cur][kk][r0];
      const float4 wv = *(const float4*)&sm->W[cur][kk][c0];
      const float xs_[4] = {xv.x,xv.y,xv.z,xv.w};
      const float ws_[4] = {wv.x,wv.y,wv.z,wv.w};
      #pragma unroll
      for (int i = 0; i < 4; ++i)
        #pragma unroll
        for (int j = 0; j < 4; ++j) acc[i][j] += xs_[i]*ws_[j];
    }
    const int nxt = cur ^ 1;
    #pragma unroll
    for (int c = 0; c < 4; ++c) {
      if (lo) {
        sm->X[nxt][q*4+c][lr]      = ((const float*)&xa)[c];
        sm->X[nxt][16+q*4+c][lr]   = ((const float*)&xb)[c];
        sm->W[nxt][q*4+c][64+lr]   = ((const float*)&wa)[c];
        sm->W[nxt][16+q*4+c][64+lr]= ((const float*)&wb)[c];
      } else {
        sm->W[nxt][q*4+c][lr]      = ((const float*)&wa)[c];
        sm->W[nxt][16+q*4+c][lr]   = ((const float*)&wb)[c];
      }
    }
    cur = nxt;
  }
  __syncthreads();
  #pragma unroll
  for (int kk = 0; kk < TK; ++kk) {
    const float4 xv = *(const float4*)&sm->X[cur][kk][r0];
    const float4 wv = *(const float4*)&sm->W[cur][kk][c0];
    const float xs_[4] = {xv.x,xv.y,xv.z,xv.w};
    const float ws_[4] = {wv.x,wv.y,wv.z,wv.w};
    #pragma unroll
    for (int i = 0; i < 4; ++i)
      #pragma unroll
      for (int j = 0; j < 4; ++j) acc[i][j] += xs_[i]*ws_[j];
  }
}

__device__ __forceinline__ void store_tile(const float acc[4][4], const float* bias,
                                           float* C, int ldc, int row0, int col0, bool act)
{
  const int tid = threadIdx.x;
  const int r0 = (tid>>5)*4, c0 = (tid&31)*4;
  const float4 bi = ld4(bias + col0 + c0);
  #pragma unroll
  for (int i = 0; i < 4; ++i) {
    float4 v;
    v.x = acc[i][0] + bi.x; v.y = acc[i][1] + bi.y;
    v.z = acc[i][2] + bi.z; v.w = acc[i][3] + bi.w;
    if (act) { v.x=elu_f(v.x); v.y=elu_f(v.y); v.z=elu_f(v.z); v.w=elu_f(v.w); }
    *(float4*)&C[(long)(row0+r0+i)*ldc + col0 + c0] = v;
  }
}

__global__ void __launch_bounds__(512) mlp_gemm(const float* __restrict__ X, int ldx,
                                                const float* __restrict__ W, int K,
                                                const float* __restrict__ bias,
                                                float* __restrict__ Y, int ldy,
                                                int NT, int act)
{
  __shared__ SmemT sm;
  const int u = blockIdx.x;
  const int mt = u / NT, nt = u % NT;
  float acc[4][4] = {};
  auto xld = [&](int r,int k){ return ld4(X + (long)(mt*64+r)*ldx + k); };
  auto wld = [&](int n,int k){ return ld4(W + (long)(nt*128+n)*K + k); };
  gemm_tile(&sm, xld, wld, K/TK, acc);
  store_tile(acc, bias, Y, ldy, mt*64, nt*128, act != 0);
}

__global__ void __launch_bounds__(512) emb_loss_k(const float* __restrict__ X,
                                                  const float* __restrict__ W,
                                                  const float* __restrict__ bias,
                                                  const float* __restrict__ tgt,
                                                  double* accp)
{
  __shared__ SmemT sm;
  const int u = blockIdx.x;
  const int mt = u / 8, nt = u % 8;
  float acc[4][4] = {};
  auto xld = [&](int r,int k){ return ld4(X + (long)(mt*64+r)*FEAT_ + k); };
  auto wld = [&](int n,int k){ return ld4(W + (long)(nt*128+n)*FEAT_ + k); };
  gemm_tile(&sm, xld, wld, FEAT_/TK, acc);
  const int tid = threadIdx.x;
  const int r0 = (tid>>5)*4, c0 = (tid&31)*4;
  const float4 bi = ld4(bias + nt*128 + c0);
  double ls = 0.0;
  #pragma unroll
  for (int i = 0; i < 4; ++i) {
    const float4 tv = ld4(tgt + (long)(mt*64+r0+i)*EMB_ + nt*128 + c0);
    const float d0 = tv.x - (acc[i][0]+bi.x);
    const float d1 = tv.y - (acc[i][1]+bi.y);
    const float d2 = tv.z - (acc[i][2]+bi.z);
    const float d3 = tv.w - (acc[i][3]+bi.w);
    ls += 0.5*((double)d0*d0 + (double)d1*d1 + (double)d2*d2 + (double)d3*d3);
  }
  ls = wave_sum(ls);
  if ((tid & 63) == 0) atomicAdd(accp, ls);
}

__global__ void __launch_bounds__(512) rp_loss_k(const float* __restrict__ h2,
                                                 const float* __restrict__ W2,
                                                 const float* __restrict__ b2,
                                                 const float* __restrict__ reward,
                                                 double* accp)
{
  const int tid = threadIdx.x;
  const int lane = tid & 63;
  const int wid = blockIdx.x*8 + (tid >> 6);
  double ls = 0.0;
  for (int row = wid; row < 4096; row += 512) {
    float part = 0.f;
    for (int k = lane*4; k < FEAT_; k += 64*4) {
      const float4 hv = ld4(h2 + (long)row*FEAT_ + k);
      const float4 wv = ld4(W2 + k);
      part += hv.x*wv.x + hv.y*wv.y + hv.z*wv.z + hv.w*wv.w;
    }
    #pragma unroll
    for (int o = 32; o > 0; o >>= 1) part += __shfl_down(part, o, 64);
    if (lane == 0) {
      const float mu = part + b2[0];
      const float d = reward[row] - mu;
      ls += 0.5 * (double)d * (double)d;
    }
  }
  if (lane == 0) atomicAdd(accp, ls);
}

__global__ void final_k(const double* acc, float* out)
{
  const double tot = (acc[0] + acc[1] + acc[2]) / (double)(T_STEPS * B_)
                   + 512.0 * LOG2PI_ + 0.5 * LOG2PI_;
  out[0] = (float)tot;
}

extern "C" void kernel_launch(void* const* d_in, const int* in_sizes, int n_in,
                              void* d_out, int out_size, void* d_ws, size_t ws_size,
                              hipStream_t stream) {
  Params p;
  p.emb    = (const float*)d_in[0];
  p.action = (const float*)d_in[1];
  p.reward = (const float*)d_in[2];
  p.eps    = (const float*)d_in[3];
  p.Wih  = (const float*)d_in[4];  p.bih  = (const float*)d_in[5];
  p.Whh  = (const float*)d_in[6];  p.bhh  = (const float*)d_in[7];
  p.stW0 = (const float*)d_in[8];  p.stb0 = (const float*)d_in[9];
  p.stW1 = (const float*)d_in[10]; p.stb1 = (const float*)d_in[11];
  p.stW2 = (const float*)d_in[12]; p.stb2 = (const float*)d_in[13];
  p.epW0 = (const float*)d_in[14]; p.epb0 = (const float*)d_in[15];
  p.epW1 = (const float*)d_in[16]; p.epb1 = (const float*)d_in[17];
  p.epW2 = (const float*)d_in[18]; p.epb2 = (const float*)d_in[19];
  const float* rpW0 = (const float*)d_in[20]; const float* rpb0 = (const float*)d_in[21];
  const float* rpW1 = (const float*)d_in[22]; const float* rpb1 = (const float*)d_in[23];
  const float* rpW2 = (const float*)d_in[24]; const float* rpb2 = (const float*)d_in[25];

  p.acc = (double*)d_ws;
  float* f = (float*)((char*)d_ws + 256);
  p.states = f;            f += (long)16384 * STATE_;
  float* h1 = f;           f += (long)4096 * FEAT_;
  float* h2 = f;           f += (long)4096 * FEAT_;
  p.out = (float*)d_out;

  hipMemsetAsync(d_ws, 0, 256, stream);

  scan_kernel<<<B_, 512, 0, stream>>>(p);

  for (int ch = 0; ch < 4; ++ch) {
    const float* xs = p.states + (long)ch*4096*STATE_;
    mlp_gemm<<<64*4, 512, 0, stream>>>(xs, STATE_, p.epW0, STATE_, p.epb0, h1, FEAT_, 4, 1);
    mlp_gemm<<<64*4, 512, 0, stream>>>(h1, FEAT_, p.epW1, FEAT_, p.epb1, h2, FEAT_, 4, 1);
    emb_loss_k<<<64*8, 512, 0, stream>>>(h2, p.epW2, p.epb2,
                                         p.emb + (long)ch*4096*EMB_, p.acc + 1);
  }
  for (int ch = 0; ch < 4; ++ch) {
    const float* xs = p.states + (long)ch*4096*STATE_;
    mlp_gemm<<<64*4, 512, 0, stream>>>(xs, STATE_, rpW0, STATE_, rpb0, h1, FEAT_, 4, 1);
    mlp_gemm<<<64*4, 512, 0, stream>>>(h1, FEAT_, rpW1, FEAT_, rpb1, h2, FEAT_, 4, 1);
    rp_loss_k<<<64, 512, 0, stream>>>(h2, rpW2, rpb2, p.reward + (long)ch*4096, p.acc + 2);
  }
  final_k<<<1, 1, 0, stream>>>(p.acc, p.out);
}

// Round 8
// 12046.834 us; speedup vs baseline: 2.3929x; 1.1270x over previous
//
#include <hip/hip_runtime.h>
#include <math.h>

typedef unsigned short u16;

#define T_STEPS 64
#define B_      256
#define EMB_    1024
#define ACT_    6
#define STOCH_  64
#define HID_    512
#define FEAT_   512
#define STATE_  576
#define G3      1536
#define TK      32
#define XPAD    68
#define WPAD    132
#define LOG2PI_ 1.8378770664093453

struct Params {
  const float *emb,*action,*reward,*eps;
  const float *bih,*bhh,*stb0,*stb1,*stb2,*epb0,*epb1,*epb2;
  const u16 *bWih,*bWhh,*bstW0,*bstW1,*bstW2,*bepW0,*bepW1,*bepW2;
  float *states;
  double *acc;   // [0]=kl [1]=emb [2]=reward
  float *out;
};

__device__ __forceinline__ float4 ld4(const float* p){ return *(const float4*)p; }
__device__ __forceinline__ float elu_f(float x){ return x > 0.f ? x : expm1f(x); }
__device__ __forceinline__ float sigmoid_f(float x){ return 1.f/(1.f+expf(-x)); }
__device__ __forceinline__ float softplus_f(float x){ return x > 20.f ? x : log1pf(expf(x)); }
__device__ __forceinline__ float blo(unsigned u){ return __uint_as_float(u << 16); }
__device__ __forceinline__ float bhi(unsigned u){ return __uint_as_float(u & 0xFFFF0000u); }
__device__ __forceinline__ float qred(float a){   // reduce over 4-lane cluster
  a += __shfl_xor(a, 1, 64);
  a += __shfl_xor(a, 2, 64);
  return a;
}
__device__ __forceinline__ double wave_sum(double v){
  #pragma unroll
  for (int o = 32; o > 0; o >>= 1) v += __shfl_down(v, o, 64);
  return v;
}

// ---------------- weight converters (fp32 -> bf16 RNE) — R5-proven ----------------
__global__ void convw_k(const float* __restrict__ s, u16* __restrict__ d, int n){
  const int i = blockIdx.x*256 + threadIdx.x;
  if (i < n){
    const unsigned u = __float_as_uint(s[i]);
    d[i] = (u16)((u + 0x7FFFu + ((u>>16)&1u)) >> 16);
  }
}
// Wih [1536][70] -> padded [1536][96] bf16 (zero pad)
__global__ void convwih_k(const float* __restrict__ s, u16* __restrict__ d){
  const int i = blockIdx.x*256 + threadIdx.x;   // < 1536*96
  const int n = i/96, k = i%96;
  u16 r = 0;
  if (k < 70){
    const unsigned u = __float_as_uint(s[n*70 + k]);
    r = (u16)((u + 0x7FFFu + ((u>>16)&1u)) >> 16);
  }
  d[i] = r;
}

// ---------------- scan GEMV cores: bf16 W via uint4 loads, fp32 x/accum ----------------
// 4-lane cluster, TWO output rows n0,n1 per pass sharing one x stream.
// lane l covers k = l*8 + 32*j; uint4 = 8 bf16: u32 low half = element k (LE).

template<int K>
__device__ __forceinline__ void gemv2b(const u16* __restrict__ W, const float* x,
                                       int n0, int n1, int l, float& y0, float& y1){
  const u16* w0 = W + (long)n0*K + l*8;
  const u16* w1 = W + (long)n1*K + l*8;
  const float* xr = x + l*8;
  float p0=0.f,p1=0.f,p2=0.f,p3=0.f, q0=0.f,q1=0.f,q2=0.f,q3=0.f;
  for (int j = 0; j < K/32; ++j){
    const uint4 a = *(const uint4*)(w0 + 32*j);
    const uint4 b = *(const uint4*)(w1 + 32*j);
    const float4 xa = ld4(xr + 32*j);
    const float4 xb = ld4(xr + 32*j + 4);
    p0 += blo(a.x)*xa.x + bhi(a.x)*xa.y;
    p1 += blo(a.y)*xa.z + bhi(a.y)*xa.w;
    p2 += blo(a.z)*xb.x + bhi(a.z)*xb.y;
    p3 += blo(a.w)*xb.z + bhi(a.w)*xb.w;
    q0 += blo(b.x)*xa.x + bhi(b.x)*xa.y;
    q1 += blo(b.y)*xa.z + bhi(b.y)*xa.w;
    q2 += blo(b.z)*xb.x + bhi(b.z)*xb.y;
    q3 += blo(b.w)*xb.z + bhi(b.w)*xb.w;
  }
  y0 = qred((p0+p1)+(p2+p3));
  y1 = qred((q0+q1)+(q2+q3));
}

// st0: K=1536 = 512 head (shared x = h_t) + 1024 tail (xA=emb_prev posterior, xB=pre_emb prior)
__device__ __forceinline__ void st0q(const u16* __restrict__ W, const float* xh,
                                     const float* xA, const float* xB,
                                     int n0, int n1, int l,
                                     float& pA0, float& pA1, float& pB0, float& pB1){
  const u16* w0 = W + (long)n0*G3 + l*8;
  const u16* w1 = W + (long)n1*G3 + l*8;
  float h0=0.f, h1=0.f;
  for (int j = 0; j < 16; ++j){
    const uint4 a = *(const uint4*)(w0 + 32*j);
    const uint4 b = *(const uint4*)(w1 + 32*j);
    const float4 xa = ld4(xh + l*8 + 32*j);
    const float4 xb = ld4(xh + l*8 + 32*j + 4);
    h0 += blo(a.x)*xa.x + bhi(a.x)*xa.y + blo(a.y)*xa.z + bhi(a.y)*xa.w
        + blo(a.z)*xb.x + bhi(a.z)*xb.y + blo(a.w)*xb.z + bhi(a.w)*xb.w;
    h1 += blo(b.x)*xa.x + bhi(b.x)*xa.y + blo(b.y)*xa.z + bhi(b.y)*xa.w
        + blo(b.z)*xb.x + bhi(b.z)*xb.y + blo(b.w)*xb.z + bhi(b.w)*xb.w;
  }
  float a0=0.f, a1=0.f, c0=0.f, c1=0.f;
  for (int j = 0; j < 32; ++j){
    const uint4 a = *(const uint4*)(w0 + 512 + 32*j);
    const uint4 b = *(const uint4*)(w1 + 512 + 32*j);
    const float4 va = ld4(xA + l*8 + 32*j);
    const float4 vb = ld4(xA + l*8 + 32*j + 4);
    const float4 wa = ld4(xB + l*8 + 32*j);
    const float4 wb = ld4(xB + l*8 + 32*j + 4);
    a0 += blo(a.x)*va.x + bhi(a.x)*va.y + blo(a.y)*va.z + bhi(a.y)*va.w
        + blo(a.z)*vb.x + bhi(a.z)*vb.y + blo(a.w)*vb.z + bhi(a.w)*vb.w;
    a1 += blo(b.x)*va.x + bhi(b.x)*va.y + blo(b.y)*va.z + bhi(b.y)*va.w
        + blo(b.z)*vb.x + bhi(b.z)*vb.y + blo(b.w)*vb.z + bhi(b.w)*vb.w;
    c0 += blo(a.x)*wa.x + bhi(a.x)*wa.y + blo(a.y)*wa.z + bhi(a.y)*wa.w
        + blo(a.z)*wb.x + bhi(a.z)*wb.y + blo(a.w)*wb.z + bhi(a.w)*wb.w;
    c1 += blo(b.x)*wa.x + bhi(b.x)*wa.y + blo(b.y)*wa.z + bhi(b.y)*wa.w
        + blo(b.z)*wb.x + bhi(b.z)*wb.y + blo(b.w)*wb.z + bhi(b.w)*wb.w;
  }
  pA0 = qred(h0 + a0); pA1 = qred(h1 + a1);
  pB0 = qred(h0 + c0); pB1 = qred(h1 + c1);
}

// st1/st2: K=512, 2 rows x 2 x-streams (posterior xA / prior xB), one W stream pair.
__device__ __forceinline__ void quad2b(const u16* __restrict__ W,
                                       const float* xA, const float* xB,
                                       int n0, int n1, int l,
                                       float& pA0, float& pA1, float& pB0, float& pB1){
  const u16* w0 = W + (long)n0*512 + l*8;
  const u16* w1 = W + (long)n1*512 + l*8;
  float a0=0.f, a1=0.f, c0=0.f, c1=0.f;
  for (int j = 0; j < 16; ++j){
    const uint4 a = *(const uint4*)(w0 + 32*j);
    const uint4 b = *(const uint4*)(w1 + 32*j);
    const float4 va = ld4(xA + l*8 + 32*j);
    const float4 vb = ld4(xA + l*8 + 32*j + 4);
    const float4 wa = ld4(xB + l*8 + 32*j);
    const float4 wb = ld4(xB + l*8 + 32*j + 4);
    a0 += blo(a.x)*va.x + bhi(a.x)*va.y + blo(a.y)*va.z + bhi(a.y)*va.w
        + blo(a.z)*vb.x + bhi(a.z)*vb.y + blo(a.w)*vb.z + bhi(a.w)*vb.w;
    a1 += blo(b.x)*va.x + bhi(b.x)*va.y + blo(b.y)*va.z + bhi(b.y)*va.w
        + blo(b.z)*vb.x + bhi(b.z)*vb.y + blo(b.w)*vb.z + bhi(b.w)*vb.w;
    c0 += blo(a.x)*wa.x + bhi(a.x)*wa.y + blo(a.y)*wa.z + bhi(a.y)*wa.w
        + blo(a.z)*wb.x + bhi(a.z)*wb.y + blo(a.w)*wb.z + bhi(a.w)*wb.w;
    c1 += blo(b.x)*wa.x + bhi(b.x)*wa.y + blo(b.y)*wa.z + bhi(b.y)*wa.w
        + blo(b.z)*wb.x + bhi(b.z)*wb.y + blo(b.w)*wb.z + bhi(b.w)*wb.w;
  }
  pA0 = qred(a0); pA1 = qred(a1);
  pB0 = qred(c0); pB1 = qred(c1);
}

// ---------------- scan kernel: one block per batch row, 512 threads (R6 structure) ------
__global__ void __launch_bounds__(512) scan_kernel(Params p)
{
  const int tid = threadIdx.x;
  const int r = blockIdx.x;
  const int c = tid >> 2, l = tid & 3;   // 128 clusters of 4 lanes

  __shared__ __align__(16) float hs[STATE_];   // [h(512) | s(64)]
  __shared__ __align__(16) float sa[96];       // [s(64) | a(6) | 0-pad]
  __shared__ __align__(16) float ep_[EMB_];
  __shared__ __align__(16) float pe0[512], pe1[512];
  __shared__ __align__(16) float pemb[EMB_];
  __shared__ __align__(16) float gi[G3], gh[G3];
  __shared__ __align__(16) float po0[512], po1[512], pr0[512], pr1[512];
  __shared__ __align__(16) float po2[128], pr2[128];

  double klacc = 0.0;
  hs[tid] = 0.f;
  if (tid < 64) hs[512 + tid] = 0.f;   // FIX: s0 was uninitialized with 512 threads
  __syncthreads();

  for (int t = 0; t < T_STEPS; ++t){
    // ---- prologue: emb_prev row + sa = [s_{t-1} | a_t | 0] ----
    {
      const long eb = ((long)(t > 0 ? t-1 : 0)*B_ + r)*EMB_;
      ep_[tid]       = p.emb[eb + tid];
      ep_[tid + 512] = p.emb[eb + 512 + tid];
      if (tid < 96){
        float v = 0.f;
        if (tid < 64)      v = hs[512 + tid];
        else if (tid < 70) v = p.action[((long)t*B_ + r)*ACT_ + (tid - 64)];
        sa[tid] = v;
      }
    }
    __syncthreads();
    // ---- S_A: pe0 (2p), gh (6p), gi (6p) — all read h/s_{t-1} ----
    for (int ps = 0; ps < 2; ++ps){
      const int n0 = ps*256 + c, n1 = n0 + 128;
      float y0, y1;
      gemv2b<STATE_>(p.bepW0, hs, n0, n1, l, y0, y1);
      if (l == 0){
        pe0[n0] = elu_f(y0 + p.epb0[n0]);
        pe0[n1] = elu_f(y1 + p.epb0[n1]);
      }
    }
    for (int ps = 0; ps < 6; ++ps){
      const int n0 = ps*256 + c, n1 = n0 + 128;
      float y0, y1;
      gemv2b<HID_>(p.bWhh, hs, n0, n1, l, y0, y1);
      if (l == 0){
        gh[n0] = y0 + p.bhh[n0];
        gh[n1] = y1 + p.bhh[n1];
      }
    }
    for (int ps = 0; ps < 6; ++ps){
      const int n0 = ps*256 + c, n1 = n0 + 128;
      float y0, y1;
      gemv2b<96>(p.bWih, sa, n0, n1, l, y0, y1);
      if (l == 0){
        gi[n0] = y0 + p.bih[n0];
        gi[n1] = y1 + p.bih[n1];
      }
    }
    __syncthreads();
    // ---- S_B: pe1 (2p) ----
    for (int ps = 0; ps < 2; ++ps){
      const int n0 = ps*256 + c, n1 = n0 + 128;
      float y0, y1;
      gemv2b<FEAT_>(p.bepW1, pe0, n0, n1, l, y0, y1);
      if (l == 0){
        pe1[n0] = elu_f(y0 + p.epb1[n0]);
        pe1[n1] = elu_f(y1 + p.epb1[n1]);
      }
    }
    __syncthreads();
    // ---- S_C: pemb (4p) + GRU combine -> h_t (disjoint LDS) ----
    for (int ps = 0; ps < 4; ++ps){
      const int n0 = ps*256 + c, n1 = n0 + 128;
      float y0, y1;
      gemv2b<FEAT_>(p.bepW2, pe1, n0, n1, l, y0, y1);
      if (l == 0){
        pemb[n0] = y0 + p.epb2[n0];
        pemb[n1] = y1 + p.epb2[n1];
      }
    }
    {
      const int j = tid;
      const float ir = gi[j], iz = gi[512+j], in_ = gi[1024+j];
      const float hr = gh[j], hz = gh[512+j], hn  = gh[1024+j];
      const float rr = sigmoid_f(ir + hr);
      const float z  = sigmoid_f(iz + hz);
      const float nn = tanhf(in_ + rr*hn);
      const float hv = (1.f - z)*nn + z*hs[j];
      hs[j] = hv;
      p.states[((long)t*B_ + r)*STATE_ + j] = hv;
    }
    __syncthreads();
    // ---- S_D: st0 quad (2p) ----
    for (int ps = 0; ps < 2; ++ps){
      const int n0 = ps*256 + c, n1 = n0 + 128;
      float pA0, pA1, pB0, pB1;
      st0q(p.bstW0, hs, ep_, pemb, n0, n1, l, pA0, pA1, pB0, pB1);
      if (l == 0){
        po0[n0] = elu_f(pA0 + p.stb0[n0]);
        po0[n1] = elu_f(pA1 + p.stb0[n1]);
        pr0[n0] = elu_f(pB0 + p.stb0[n0]);
        pr0[n1] = elu_f(pB1 + p.stb0[n1]);
      }
    }
    __syncthreads();
    // ---- S_E: st1 quad (2p) ----
    for (int ps = 0; ps < 2; ++ps){
      const int n0 = ps*256 + c, n1 = n0 + 128;
      float pA0, pA1, pB0, pB1;
      quad2b(p.bstW1, po0, pr0, n0, n1, l, pA0, pA1, pB0, pB1);
      if (l == 0){
        po1[n0] = elu_f(pA0 + p.stb1[n0]);
        po1[n1] = elu_f(pA1 + p.stb1[n1]);
        pr1[n0] = elu_f(pB0 + p.stb1[n0]);
        pr1[n1] = elu_f(pB1 + p.stb1[n1]);
      }
    }
    __syncthreads();
    // ---- S_F: st2 quad (1p, clusters 0..63) ----
    if (c < 64){
      const int n0 = c, n1 = c + 64;
      float pA0, pA1, pB0, pB1;
      quad2b(p.bstW2, po1, pr1, n0, n1, l, pA0, pA1, pB0, pB1);
      if (l == 0){
        po2[n0] = pA0 + p.stb2[n0];
        po2[n1] = pA1 + p.stb2[n1];
        pr2[n0] = pB0 + p.stb2[n0];
        pr2[n1] = pB1 + p.stb2[n1];
      }
    }
    __syncthreads();
    // ---- S_G: KL(t) + sample s_t ----
    if (tid < 64){
      const int j = tid;
      const float qmu = po2[j],  qsr = po2[64+j];
      const float pmu = pr2[j],  psr = pr2[64+j];
      const float qstd = softplus_f(qsr) + 1e-4f;
      const float pstd = softplus_f(psr) + 1e-4f;
      const float dm = qmu - pmu;
      klacc += (double)(logf(pstd/qstd) + (qstd*qstd + dm*dm)/(2.f*pstd*pstd) - 0.5f);
      const float sv = qmu + qstd * p.eps[((long)t*B_ + r)*STOCH_ + j];
      hs[512 + j] = sv;
      p.states[((long)t*B_ + r)*STATE_ + 512 + j] = sv;
    }
    __syncthreads();
  }

  if (tid < 64){
    const double s = wave_sum(klacc);
    if (tid == 0) atomicAdd(&p.acc[0], s);
  }
}

// ---------------- tail head kernels (R4/R6-proven, byte-identical) ----------------

struct SmemT { float X[2][TK][XPAD]; float W[2][TK][WPAD]; };

template<class XLD, class WLD>
__device__ __forceinline__ void gemm_tile(SmemT* sm, XLD xld, WLD wld, int nkt, float acc[4][4])
{
  const int tid = threadIdx.x;
  const int r0 = (tid >> 5) * 4;
  const int c0 = (tid & 31) * 4;
  const int sr = tid & 255;
  const int lr = sr >> 2, q = sr & 3;
  const bool lo = tid < 256;
  float4 xa, xb, wa, wb;
  if (lo) { xa = xld(lr, q*4);      xb = xld(lr, 16 + q*4);
            wa = wld(64+lr, q*4);   wb = wld(64+lr, 16 + q*4); }
  else    { wa = wld(lr, q*4);      wb = wld(lr, 16 + q*4); }
  int cur = 0;
  #pragma unroll
  for (int c = 0; c < 4; ++c) {
    if (lo) {
      sm->X[0][q*4+c][lr]      = ((const float*)&xa)[c];
      sm->X[0][16+q*4+c][lr]   = ((const float*)&xb)[c];
      sm->W[0][q*4+c][64+lr]   = ((const float*)&wa)[c];
      sm->W[0][16+q*4+c][64+lr]= ((const float*)&wb)[c];
    } else {
      sm->W[0][q*4+c][lr]      = ((const float*)&wa)[c];
      sm->W[0][16+q*4+c][lr]   = ((const float*)&wb)[c];
    }
  }
  for (int kt = 1; kt < nkt; ++kt) {
    __syncthreads();
    const int kb = kt*TK;
    if (lo) { xa = xld(lr, kb + q*4);    xb = xld(lr, kb + 16 + q*4);
              wa = wld(64+lr, kb + q*4); wb = wld(64+lr, kb + 16 + q*4); }
    else    { wa = wld(lr, kb + q*4);    wb = wld(lr, kb + 16 + q*4); }
    #pragma unroll
    for (int kk = 0; kk < TK; ++kk) {
      const float4 xv = *(const float4*)&sm->X[cur][kk][r0];
      const float4 wv = *(const float4*)&sm->W[cur][kk][c0];
      const float xs_[4] = {xv.x,xv.y,xv.z,xv.w};
      const float ws_[4] = {wv.x,wv.y,wv.z,wv.w};
      #pragma unroll
      for (int i = 0; i < 4; ++i)
        #pragma unroll
        for (int j = 0; j < 4; ++j) acc[i][j] += xs_[i]*ws_[j];
    }
    const int nxt = cur ^ 1;
    #pragma unroll
    for (int c = 0; c < 4; ++c) {
      if (lo) {
        sm->X[nxt][q*4+c][lr]      = ((const float*)&xa)[c];
        sm->X[nxt][16+q*4+c][lr]   = ((const float*)&xb)[c];
        sm->W[nxt][q*4+c][64+lr]   = ((const float*)&wa)[c];
        sm->W[nxt][16+q*4+c][64+lr]= ((const float*)&wb)[c];
      } else {
        sm->W[nxt][q*4+c][lr]      = ((const float*)&wa)[c];
        sm->W[nxt][16+q*4+c][lr]   = ((const float*)&wb)[c];
      }
    }
    cur = nxt;
  }
  __syncthreads();
  #pragma unroll
  for (int kk = 0; kk < TK; ++kk) {
    const float4 xv = *(const float4*)&sm->X[cur][kk][r0];
    const float4 wv = *(const float4*)&sm->W[cur][kk][c0];
    const float xs_[4] = {xv.x,xv.y,xv.z,xv.w};
    const float ws_[4] = {wv.x,wv.y,wv.z,wv.w};
    #pragma unroll
    for (int i = 0; i < 4; ++i)
      #pragma unroll
      for (int j = 0; j < 4; ++j) acc[i][j] += xs_[i]*ws_[j];
  }
}

__device__ __forceinline__ void store_tile(const float acc[4][4], const float* bias,
                                           float* C, int ldc, int row0, int col0, bool act)
{
  const int tid = threadIdx.x;
  const int r0 = (tid>>5)*4, c0 = (tid&31)*4;
  const float4 bi = ld4(bias + col0 + c0);
  #pragma unroll
  for (int i = 0; i < 4; ++i) {
    float4 v;
    v.x = acc[i][0] + bi.x; v.y = acc[i][1] + bi.y;
    v.z = acc[i][2] + bi.z; v.w = acc[i][3] + bi.w;
    if (act) { v.x=elu_f(v.x); v.y=elu_f(v.y); v.z=elu_f(v.z); v.w=elu_f(v.w); }
    *(float4*)&C[(long)(row0+r0+i)*ldc + col0 + c0] = v;
  }
}

__global__ void __launch_bounds__(512) mlp_gemm(const float* __restrict__ X, int ldx,
                                                const float* __restrict__ W, int K,
                                                const float* __restrict__ bias,
                                                float* __restrict__ Y, int ldy,
                                                int NT, int act)
{
  __shared__ SmemT sm;
  const int u = blockIdx.x;
  const int mt = u / NT, nt = u % NT;
  float acc[4][4] = {};
  auto xld = [&](int r,int k){ return ld4(X + (long)(mt*64+r)*ldx + k); };
  auto wld = [&](int n,int k){ return ld4(W + (long)(nt*128+n)*K + k); };
  gemm_tile(&sm, xld, wld, K/TK, acc);
  store_tile(acc, bias, Y, ldy, mt*64, nt*128, act != 0);
}

__device__ __forceinline__ double wave_sum_d(double v){
  #pragma unroll
  for (int o = 32; o > 0; o >>= 1) v += __shfl_down(v, o, 64);
  return v;
}

__global__ void __launch_bounds__(512) emb_loss_k(const float* __restrict__ X,
                                                  const float* __restrict__ W,
                                                  const float* __restrict__ bias,
                                                  const float* __restrict__ tgt,
                                                  double* accp)
{
  __shared__ SmemT sm;
  const int u = blockIdx.x;
  const int mt = u / 8, nt = u % 8;
  float acc[4][4] = {};
  auto xld = [&](int r,int k){ return ld4(X + (long)(mt*64+r)*FEAT_ + k); };
  auto wld = [&](int n,int k){ return ld4(W + (long)(nt*128+n)*FEAT_ + k); };
  gemm_tile(&sm, xld, wld, FEAT_/TK, acc);
  const int tid = threadIdx.x;
  const int r0 = (tid>>5)*4, c0 = (tid&31)*4;
  const float4 bi = ld4(bias + nt*128 + c0);
  double ls = 0.0;
  #pragma unroll
  for (int i = 0; i < 4; ++i) {
    const float4 tv = ld4(tgt + (long)(mt*64+r0+i)*EMB_ + nt*128 + c0);
    const float d0 = tv.x - (acc[i][0]+bi.x);
    const float d1 = tv.y - (acc[i][1]+bi.y);
    const float d2 = tv.z - (acc[i][2]+bi.z);
    const float d3 = tv.w - (acc[i][3]+bi.w);
    ls += 0.5*((double)d0*d0 + (double)d1*d1 + (double)d2*d2 + (double)d3*d3);
  }
  ls = wave_sum_d(ls);
  if ((tid & 63) == 0) atomicAdd(accp, ls);
}

__global__ void __launch_bounds__(512) rp_loss_k(const float* __restrict__ h2,
                                                 const float* __restrict__ W2,
                                                 const float* __restrict__ b2,
                                                 const float* __restrict__ reward,
                                                 double* accp)
{
  const int tid = threadIdx.x;
  const int lane = tid & 63;
  const int wid = blockIdx.x*8 + (tid >> 6);
  double ls = 0.0;
  for (int row = wid; row < 4096; row += 512) {
    float part = 0.f;
    for (int k = lane*4; k < FEAT_; k += 64*4) {
      const float4 hv = ld4(h2 + (long)row*FEAT_ + k);
      const float4 wv = ld4(W2 + k);
      part += hv.x*wv.x + hv.y*wv.y + hv.z*wv.z + hv.w*wv.w;
    }
    #pragma unroll
    for (int o = 32; o > 0; o >>= 1) part += __shfl_down(part, o, 64);
    if (lane == 0) {
      const float mu = part + b2[0];
      const float d = reward[row] - mu;
      ls += 0.5 * (double)d * (double)d;
    }
  }
  if (lane == 0) atomicAdd(accp, ls);
}

__global__ void final_k(const double* acc, float* out)
{
  const double tot = (acc[0] + acc[1] + acc[2]) / (double)(T_STEPS * B_)
                   + 512.0 * LOG2PI_ + 0.5 * LOG2PI_;
  out[0] = (float)tot;
}

extern "C" void kernel_launch(void* const* d_in, const int* in_sizes, int n_in,
                              void* d_out, int out_size, void* d_ws, size_t ws_size,
                              hipStream_t stream) {
  const float* emb    = (const float*)d_in[0];
  const float* action = (const float*)d_in[1];
  const float* reward = (const float*)d_in[2];
  const float* eps    = (const float*)d_in[3];
  const float* Wih  = (const float*)d_in[4];  const float* bih  = (const float*)d_in[5];
  const float* Whh  = (const float*)d_in[6];  const float* bhh  = (const float*)d_in[7];
  const float* stW0 = (const float*)d_in[8];  const float* stb0 = (const float*)d_in[9];
  const float* stW1 = (const float*)d_in[10]; const float* stb1 = (const float*)d_in[11];
  const float* stW2 = (const float*)d_in[12]; const float* stb2 = (const float*)d_in[13];
  const float* epW0 = (const float*)d_in[14]; const float* epb0 = (const float*)d_in[15];
  const float* epW1 = (const float*)d_in[16]; const float* epb1 = (const float*)d_in[17];
  const float* epW2 = (const float*)d_in[18]; const float* epb2 = (const float*)d_in[19];
  const float* rpW0 = (const float*)d_in[20]; const float* rpb0 = (const float*)d_in[21];
  const float* rpW1 = (const float*)d_in[22]; const float* rpb1 = (const float*)d_in[23];
  const float* rpW2 = (const float*)d_in[24]; const float* rpb2 = (const float*)d_in[25];

  double* acc = (double*)d_ws;
  float* f = (float*)((char*)d_ws + 256);
  float* states = f;  f += (long)16384 * STATE_;
  float* h1 = f;      f += (long)4096 * FEAT_;
  float* h2 = f;      f += (long)4096 * FEAT_;
  u16* bw = (u16*)f;
  u16* bepW0 = bw;    bw += 294912;
  u16* bepW1 = bw;    bw += 262144;
  u16* bepW2 = bw;    bw += 524288;
  u16* bWhh  = bw;    bw += 786432;
  u16* bstW0 = bw;    bw += 786432;
  u16* bstW1 = bw;    bw += 262144;
  u16* bstW2 = bw;    bw += 65536;
  u16* bWih  = bw;    bw += 147456;
  // total ws ~58 MB (< 64 MiB cap inferred from R2 launch failure)

  hipMemsetAsync(d_ws, 0, 256, stream);

  convw_k<<<(294912+255)/256, 256, 0, stream>>>(epW0, bepW0, 294912);
  convw_k<<<(262144+255)/256, 256, 0, stream>>>(epW1, bepW1, 262144);
  convw_k<<<(524288+255)/256, 256, 0, stream>>>(epW2, bepW2, 524288);
  convw_k<<<(786432+255)/256, 256, 0, stream>>>(Whh,  bWhh,  786432);
  convw_k<<<(786432+255)/256, 256, 0, stream>>>(stW0, bstW0, 786432);
  convw_k<<<(262144+255)/256, 256, 0, stream>>>(stW1, bstW1, 262144);
  convw_k<<<(65536+255)/256,  256, 0, stream>>>(stW2, bstW2, 65536);
  convwih_k<<<(147456+255)/256, 256, 0, stream>>>(Wih, bWih);

  Params p;
  p.emb = emb; p.action = action; p.reward = reward; p.eps = eps;
  p.bih = bih; p.bhh = bhh;
  p.stb0 = stb0; p.stb1 = stb1; p.stb2 = stb2;
  p.epb0 = epb0; p.epb1 = epb1; p.epb2 = epb2;
  p.bWih = bWih; p.bWhh = bWhh;
  p.bstW0 = bstW0; p.bstW1 = bstW1; p.bstW2 = bstW2;
  p.bepW0 = bepW0; p.bepW1 = bepW1; p.bepW2 = bepW2;
  p.states = states;
  p.acc = acc;
  p.out = (float*)d_out;

  scan_kernel<<<B_, 512, 0, stream>>>(p);

  for (int ch = 0; ch < 4; ++ch) {
    const float* xs = states + (long)ch*4096*STATE_;
    mlp_gemm<<<64*4, 512, 0, stream>>>(xs, STATE_, epW0, STATE_, epb0, h1, FEAT_, 4, 1);
    mlp_gemm<<<64*4, 512, 0, stream>>>(h1, FEAT_, epW1, FEAT_, epb1, h2, FEAT_, 4, 1);
    emb_loss_k<<<64*8, 512, 0, stream>>>(h2, epW2, epb2, emb + (long)ch*4096*EMB_, acc + 1);
  }
  for (int ch = 0; ch < 4; ++ch) {
    const float* xs = states + (long)ch*4096*STATE_;
    mlp_gemm<<<64*4, 512, 0, stream>>>(xs, STATE_, rpW0, STATE_, rpb0, h1, FEAT_, 4, 1);
    mlp_gemm<<<64*4, 512, 0, stream>>>(h1, FEAT_, rpW1, FEAT_, rpb1, h2, FEAT_, 4, 1);
    rp_loss_k<<<64, 512, 0, stream>>>(h2, rpW2, rpb2, reward + (long)ch*4096, acc + 2);
  }
  final_k<<<1, 1, 0, stream>>>(acc, p.out);
}